// Round 1
// baseline (1625.420 us; speedup 1.0000x reference)
//
#include <hip/hip_runtime.h>
#include <math.h>

#define NLV 16
#define TBL (1u << 19)

struct ResArr { float r[NLV]; };

__global__ __launch_bounds__(256)
void ngp_fwd_kernel(const float* __restrict__ positions,
                    const float* __restrict__ aabb,
                    const float* __restrict__ table,
                    const float* __restrict__ w1, const float* __restrict__ b1,
                    const float* __restrict__ w2, const float* __restrict__ b2,
                    const float* __restrict__ hw1, const float* __restrict__ hb1,
                    const float* __restrict__ hw2, const float* __restrict__ hb2,
                    const float* __restrict__ hw3, const float* __restrict__ hb3,
                    float* __restrict__ out, int npts, ResArr res)
{
    const int p = blockIdx.x * blockDim.x + threadIdx.x;
    if (p >= npts) return;

    const float px = positions[p * 3 + 0];
    const float py = positions[p * 3 + 1];
    const float pz = positions[p * 3 + 2];

    const float mnx = aabb[0], mny = aabb[1], mnz = aabb[2];
    const float mxx = aabb[3], mxy = aabb[4], mxz = aabb[5];

    const float x0 = (px - mnx) / (mxx - mnx);
    const float x1 = (py - mny) / (mxy - mny);
    const float x2 = (pz - mnz) / (mxz - mnz);

    const bool sel = (x0 > 0.f) && (x0 < 1.f) &&
                     (x1 > 0.f) && (x1 < 1.f) &&
                     (x2 > 0.f) && (x2 < 1.f);

    // ---- hash encoding: 16 levels x 2 features ----
    float enc[2 * NLV];
    #pragma unroll
    for (int l = 0; l < NLV; ++l) {
        const float r = res.r[l];
        const float fx = x0 * r, fy = x1 * r, fz = x2 * r;
        const float gx = floorf(fx), gy = floorf(fy), gz = floorf(fz);
        const unsigned cx = (unsigned)gx, cy = (unsigned)gy, cz = (unsigned)gz;
        const float rx = fx - gx, ry = fy - gy, rz = fz - gz;
        const float* tl = table + (size_t)l * TBL * 2;
        float e0 = 0.f, e1 = 0.f;
        #pragma unroll
        for (int c = 0; c < 8; ++c) {
            const unsigned hx = cx + ((c >> 2) & 1);
            const unsigned hy = cy + ((c >> 1) & 1);
            const unsigned hz = cz + (c & 1);
            const unsigned h =
                (hx * 1u ^ hy * 2654435761u ^ hz * 805459861u) & (TBL - 1u);
            const float wx = (c & 4) ? rx : 1.f - rx;
            const float wy = (c & 2) ? ry : 1.f - ry;
            const float wz = (c & 1) ? rz : 1.f - rz;
            const float wgt = wx * wy * wz;
            const float2 f = *reinterpret_cast<const float2*>(tl + (size_t)h * 2u);
            e0 = fmaf(wgt, f.x, e0);
            e1 = fmaf(wgt, f.y, e1);
        }
        enc[2 * l + 0] = e0;
        enc[2 * l + 1] = e1;
    }

    // ---- h1 = relu(enc @ w1 + b1)   (32 x 64) ----
    float h1[64];
    #pragma unroll
    for (int j = 0; j < 64; ++j) h1[j] = b1[j];
    #pragma unroll
    for (int i = 0; i < 32; ++i) {
        const float e = enc[i];
        #pragma unroll
        for (int j = 0; j < 64; ++j) h1[j] = fmaf(e, w1[i * 64 + j], h1[j]);
    }
    #pragma unroll
    for (int j = 0; j < 64; ++j) h1[j] = fmaxf(h1[j], 0.f);

    // ---- base = h1 @ w2 + b2   (64 x 16) ----
    float base[16];
    #pragma unroll
    for (int j = 0; j < 16; ++j) base[j] = b2[j];
    #pragma unroll
    for (int i = 0; i < 64; ++i) {
        const float e = h1[i];
        #pragma unroll
        for (int j = 0; j < 16; ++j) base[j] = fmaf(e, w2[i * 16 + j], base[j]);
    }

    const float density = expf(base[0] - 1.f) * (sel ? 1.f : 0.f);

    // ---- hh1 = relu(emb @ hw1 + hb1)   (15 x 64) ----
    float hh1[64];
    #pragma unroll
    for (int j = 0; j < 64; ++j) hh1[j] = hb1[j];
    #pragma unroll
    for (int i = 0; i < 15; ++i) {
        const float e = base[1 + i];
        #pragma unroll
        for (int j = 0; j < 64; ++j) hh1[j] = fmaf(e, hw1[i * 64 + j], hh1[j]);
    }
    #pragma unroll
    for (int j = 0; j < 64; ++j) hh1[j] = fmaxf(hh1[j], 0.f);

    // ---- hh2 = relu(hh1 @ hw2 + hb2) streamed directly into rgb accums ----
    float r0 = hb3[0], r1 = hb3[1], r2 = hb3[2];
    #pragma unroll
    for (int j = 0; j < 64; ++j) {
        float acc = hb2[j];
        #pragma unroll
        for (int i = 0; i < 64; ++i) acc = fmaf(hh1[i], hw2[i * 64 + j], acc);
        acc = fmaxf(acc, 0.f);
        r0 = fmaf(acc, hw3[j * 3 + 0], r0);
        r1 = fmaf(acc, hw3[j * 3 + 1], r1);
        r2 = fmaf(acc, hw3[j * 3 + 2], r2);
    }

    r0 = 1.f / (1.f + expf(-r0));
    r1 = 1.f / (1.f + expf(-r1));
    r2 = 1.f / (1.f + expf(-r2));

    out[(size_t)p * 3 + 0] = r0;
    out[(size_t)p * 3 + 1] = r1;
    out[(size_t)p * 3 + 2] = r2;
    out[(size_t)npts * 3 + p] = density;
}

extern "C" void kernel_launch(void* const* d_in, const int* in_sizes, int n_in,
                              void* d_out, int out_size, void* d_ws, size_t ws_size,
                              hipStream_t stream) {
    const float* positions = (const float*)d_in[0];
    const float* aabb      = (const float*)d_in[1];
    const float* table     = (const float*)d_in[2];
    const float* w1  = (const float*)d_in[3];
    const float* b1  = (const float*)d_in[4];
    const float* w2  = (const float*)d_in[5];
    const float* b2  = (const float*)d_in[6];
    const float* hw1 = (const float*)d_in[7];
    const float* hb1 = (const float*)d_in[8];
    const float* hw2 = (const float*)d_in[9];
    const float* hb2 = (const float*)d_in[10];
    const float* hw3 = (const float*)d_in[11];
    const float* hb3 = (const float*)d_in[12];
    float* out = (float*)d_out;

    const int npts = in_sizes[0] / 3;

    // RES computed exactly as the numpy reference does (float64 -> floor -> f32).
    ResArr res;
    const double bb = exp((log(4096.0) - log(16.0)) / 15.0);
    for (int l = 0; l < NLV; ++l)
        res.r[l] = (float)floor(16.0 * pow(bb, (double)l));

    const int threads = 256;
    const int blocks = (npts + threads - 1) / threads;
    ngp_fwd_kernel<<<blocks, threads, 0, stream>>>(
        positions, aabb, table, w1, b1, w2, b2,
        hw1, hb1, hw2, hb2, hw3, hb3, out, npts, res);
}

// Round 2
// 582.928 us; speedup vs baseline: 2.7884x; 2.7884x over previous
//
#include <hip/hip_runtime.h>
#include <math.h>

#define NLV 16
#define TBLBITS 19
#define TBLMASK ((1u << TBLBITS) - 1u)

typedef __attribute__((ext_vector_type(8))) short bf16x8;
typedef __attribute__((ext_vector_type(4))) float f32x4;

__device__ __forceinline__ unsigned f2bf(float f) {
    unsigned u = __builtin_bit_cast(unsigned, f);
    return (u + 0x7fffu + ((u >> 16) & 1u)) >> 16;   // RNE to bf16
}

// ---------------- Kernel A: hash-grid encode, one thread per (point, level) --
__global__ __launch_bounds__(256)
void enc_kernel(const float* __restrict__ positions,
                const float* __restrict__ aabb,
                const float* __restrict__ table,
                unsigned* __restrict__ encOut,
                float r0_, float r1_, float r2_, float r3_,
                float r4_, float r5_, float r6_, float r7_,
                float r8_, float r9_, float r10_, float r11_,
                float r12_, float r13_, float r14_, float r15_)
{
    const unsigned t = blockIdx.x * 256u + threadIdx.x;
    const unsigned l = t & 15u;
    const unsigned p = t >> 4;

    // res select via cndmask tree (no dynamically-indexed array -> no scratch)
    const bool s0 = (l & 1u), s1 = (l & 2u), s2 = (l & 4u), s3 = (l & 8u);
    float a0 = s0 ? r1_  : r0_;
    float a1 = s0 ? r3_  : r2_;
    float a2 = s0 ? r5_  : r4_;
    float a3 = s0 ? r7_  : r6_;
    float a4 = s0 ? r9_  : r8_;
    float a5 = s0 ? r11_ : r10_;
    float a6 = s0 ? r13_ : r12_;
    float a7 = s0 ? r15_ : r14_;
    float c0 = s1 ? a1 : a0;
    float c1 = s1 ? a3 : a2;
    float c2 = s1 ? a5 : a4;
    float c3 = s1 ? a7 : a6;
    float d0 = s2 ? c1 : c0;
    float d1 = s2 ? c3 : c2;
    const float r = s3 ? d1 : d0;

    const float px = positions[p * 3 + 0];
    const float py = positions[p * 3 + 1];
    const float pz = positions[p * 3 + 2];
    const float mnx = aabb[0], mny = aabb[1], mnz = aabb[2];
    const float mxx = aabb[3], mxy = aabb[4], mxz = aabb[5];
    const float x0 = (px - mnx) / (mxx - mnx);
    const float x1 = (py - mny) / (mxy - mny);
    const float x2 = (pz - mnz) / (mxz - mnz);

    const float fx = x0 * r, fy = x1 * r, fz = x2 * r;
    const float gx = floorf(fx), gy = floorf(fy), gz = floorf(fz);
    const unsigned cx = (unsigned)gx, cy = (unsigned)gy, cz = (unsigned)gz;
    const float rx = fx - gx, ry = fy - gy, rz = fz - gz;

    const float* tl = table + ((size_t)l << 20);   // l * TBL * 2 floats
    float e0 = 0.f, e1 = 0.f;
    #pragma unroll
    for (int c = 0; c < 8; ++c) {
        const unsigned hx = cx + ((c >> 2) & 1);
        const unsigned hy = cy + ((c >> 1) & 1);
        const unsigned hz = cz + (c & 1);
        const unsigned h = (hx ^ hy * 2654435761u ^ hz * 805459861u) & TBLMASK;
        const float wx = (c & 4) ? rx : 1.f - rx;
        const float wy = (c & 2) ? ry : 1.f - ry;
        const float wz = (c & 1) ? rz : 1.f - rz;
        const float wgt = wx * wy * wz;
        const float2 f = *reinterpret_cast<const float2*>(tl + ((size_t)h << 1));
        e0 = fmaf(wgt, f.x, e0);
        e1 = fmaf(wgt, f.y, e1);
    }
    encOut[t] = f2bf(e0) | (f2bf(e1) << 16);
}

// ---------------- Kernel W: transpose/pad/convert weights to bf16 frag layout
// Layout (ushort elements):
//  w1T  @     0: 64 rows, stride 40 (K=32 real 32)        from w1  [32][64]
//  w3T  @  2560: 64 rows, stride 40 (K=32 real 15)        from hw1 [15][64]
//  w2T  @  5120: 16 rows, stride 72 (K=64)                from w2  [64][16]
//  w4T  @  6272: 64 rows, stride 72 (K=64)                from hw2 [64][64]
//  w5T  @ 10880: 16 rows, stride 72 (K=64, real N=3)      from hw3 [64][3]
__global__ __launch_bounds__(256)
void prep_weights(const float* __restrict__ w1, const float* __restrict__ w2,
                  const float* __restrict__ hw1, const float* __restrict__ hw2,
                  const float* __restrict__ hw3, unsigned short* __restrict__ wt)
{
    for (int i = threadIdx.x; i < 12032; i += 256) {
        float v = 0.f;
        if (i < 2560) {
            int n = i / 40, k = i % 40;
            if (k < 32) v = w1[k * 64 + n];
        } else if (i < 5120) {
            int j = i - 2560, n = j / 40, k = j % 40;
            if (k < 15) v = hw1[k * 64 + n];
        } else if (i < 6272) {
            int j = i - 5120, n = j / 72, k = j % 72;
            if (k < 64) v = w2[k * 16 + n];
        } else if (i < 10880) {
            int j = i - 6272, n = j / 72, k = j % 72;
            if (k < 64) v = hw2[k * 64 + n];
        } else {
            int j = i - 10880, n = j / 72, k = j % 72;
            if (k < 64 && n < 3) v = hw3[k * 3 + n];
        }
        wt[i] = (unsigned short)f2bf(v);
    }
}

// ---------------- Kernel B: fused MFMA-bf16 MLP, 256 points / block ---------
__global__ __launch_bounds__(256)
void mlp_kernel(const unsigned* __restrict__ enc,        // bf16 pairs [npts][16]
                const unsigned short* __restrict__ wt,   // prepped weights
                const float* __restrict__ positions,
                const float* __restrict__ aabb,
                const float* __restrict__ b1, const float* __restrict__ b2,
                const float* __restrict__ hb1, const float* __restrict__ hb2,
                const float* __restrict__ hb3,
                float* __restrict__ out, int npts)
{
    __shared__ __align__(16) unsigned short wlds[12032];
    __shared__ __align__(16) unsigned short H[4][64 * 72];  // per-wave, stride 72
    __shared__ float sel_lds[256];

    const int tid  = threadIdx.x;
    const int wave = tid >> 6;
    const int lane = tid & 63;
    const int col  = lane & 15;
    const int lgrp = lane >> 4;
    const int blockPt = blockIdx.x * 256;

    // ---- stage weights (coalesced 16B copies) ----
    #pragma unroll
    for (int i = 0; i < 6; ++i) {
        int idx = tid + i * 256;
        if (idx < 1504)
            reinterpret_cast<uint4*>(wlds)[idx] =
                reinterpret_cast<const uint4*>(wt)[idx];
    }

    // ---- selector for own point ----
    {
        const int gp = blockPt + tid;
        const float px = positions[gp * 3 + 0];
        const float py = positions[gp * 3 + 1];
        const float pz = positions[gp * 3 + 2];
        const float mnx = aabb[0], mny = aabb[1], mnz = aabb[2];
        const float mxx = aabb[3], mxy = aabb[4], mxz = aabb[5];
        const float x0 = (px - mnx) / (mxx - mnx);
        const float x1 = (py - mny) / (mxy - mny);
        const float x2 = (pz - mnz) / (mxz - mnz);
        const bool sel = (x0 > 0.f) && (x0 < 1.f) && (x1 > 0.f) && (x1 < 1.f) &&
                         (x2 > 0.f) && (x2 < 1.f);
        sel_lds[tid] = sel ? 1.f : 0.f;
    }

    // ---- per-lane bias preloads ----
    float bias1[4], biasH1[4], biasH2[4];
    #pragma unroll
    for (int nt = 0; nt < 4; ++nt) {
        bias1[nt]  = b1[nt * 16 + col];
        biasH1[nt] = hb1[nt * 16 + col];
        biasH2[nt] = hb2[nt * 16 + col];
    }
    const float bias2 = b2[col];
    float biasH3 = 0.f;
    if (col < 3) biasH3 = hb3[col];

    // ---- A-frags for layer 1 straight from global enc ----
    bf16x8 a1[4];
    #pragma unroll
    for (int mt = 0; mt < 4; ++mt) {
        const int ptl = wave * 64 + mt * 16 + col;
        const uint4 v = *reinterpret_cast<const uint4*>(
            enc + (size_t)(blockPt + ptl) * 16 + lgrp * 4);
        a1[mt] = __builtin_bit_cast(bf16x8, v);
    }

    __syncthreads();

    const unsigned short* w1t = wlds;
    const unsigned short* w3t = wlds + 2560;
    const unsigned short* w2t = wlds + 5120;
    const unsigned short* w4t = wlds + 6272;
    const unsigned short* w5t = wlds + 10880;
    unsigned short* Hw = H[wave];

    const f32x4 zero = {0.f, 0.f, 0.f, 0.f};

    // ================= L1: h1 = relu(enc @ w1 + b1)  [K=32, N=64] ==========
    {
        f32x4 acc[4][4];
        #pragma unroll
        for (int mt = 0; mt < 4; ++mt)
            #pragma unroll
            for (int nt = 0; nt < 4; ++nt) acc[mt][nt] = zero;

        #pragma unroll
        for (int nt = 0; nt < 4; ++nt) {
            const bf16x8 b = *reinterpret_cast<const bf16x8*>(
                w1t + (nt * 16 + col) * 40 + lgrp * 8);
            #pragma unroll
            for (int mt = 0; mt < 4; ++mt)
                acc[mt][nt] = __builtin_amdgcn_mfma_f32_16x16x32_bf16(
                    a1[mt], b, acc[mt][nt], 0, 0, 0);
        }
        // relu + bias -> bf16 -> H
        #pragma unroll
        for (int mt = 0; mt < 4; ++mt)
            #pragma unroll
            for (int nt = 0; nt < 4; ++nt)
                #pragma unroll
                for (int rr = 0; rr < 4; ++rr) {
                    const float h = fmaxf(acc[mt][nt][rr] + bias1[nt], 0.f);
                    const int row = mt * 16 + lgrp * 4 + rr;
                    Hw[row * 72 + nt * 16 + col] = (unsigned short)f2bf(h);
                }
    }

    // ================= L2: base = h1 @ w2 + b2  [K=64, N=16] ================
    {
        f32x4 acc[4];
        #pragma unroll
        for (int mt = 0; mt < 4; ++mt) acc[mt] = zero;

        #pragma unroll
        for (int ks = 0; ks < 2; ++ks) {
            const bf16x8 b = *reinterpret_cast<const bf16x8*>(
                w2t + col * 72 + ks * 32 + lgrp * 8);
            #pragma unroll
            for (int mt = 0; mt < 4; ++mt) {
                const bf16x8 a = *reinterpret_cast<const bf16x8*>(
                    Hw + (mt * 16 + col) * 72 + ks * 32 + lgrp * 8);
                acc[mt] = __builtin_amdgcn_mfma_f32_16x16x32_bf16(
                    a, b, acc[mt], 0, 0, 0);
            }
        }
        // density out (col 0) / embedding -> H cols 0..14
        #pragma unroll
        for (int mt = 0; mt < 4; ++mt)
            #pragma unroll
            for (int rr = 0; rr < 4; ++rr) {
                const float base = acc[mt][rr] + bias2;
                const int row = mt * 16 + lgrp * 4 + rr;
                if (col == 0) {
                    const float dn =
                        expf(base - 1.f) * sel_lds[wave * 64 + row];
                    out[(size_t)npts * 3 + blockPt + wave * 64 + row] = dn;
                } else {
                    Hw[row * 72 + (col - 1)] = (unsigned short)f2bf(base);
                }
            }
        // zero pad cols 15..31 (one row per lane)
        {
            const int row = lane;
            Hw[row * 72 + 15] = 0;
            const uint4 z4 = {0, 0, 0, 0};
            *reinterpret_cast<uint4*>(Hw + row * 72 + 16) = z4;
            *reinterpret_cast<uint4*>(Hw + row * 72 + 24) = z4;
        }
    }

    // ================= L3: hh1 = relu(emb @ hw1 + hb1)  [K=32(15), N=64] ====
    {
        f32x4 acc[4][4];
        #pragma unroll
        for (int mt = 0; mt < 4; ++mt)
            #pragma unroll
            for (int nt = 0; nt < 4; ++nt) acc[mt][nt] = zero;

        bf16x8 a[4];
        #pragma unroll
        for (int mt = 0; mt < 4; ++mt)
            a[mt] = *reinterpret_cast<const bf16x8*>(
                Hw + (mt * 16 + col) * 72 + lgrp * 8);

        #pragma unroll
        for (int nt = 0; nt < 4; ++nt) {
            const bf16x8 b = *reinterpret_cast<const bf16x8*>(
                w3t + (nt * 16 + col) * 40 + lgrp * 8);
            #pragma unroll
            for (int mt = 0; mt < 4; ++mt)
                acc[mt][nt] = __builtin_amdgcn_mfma_f32_16x16x32_bf16(
                    a[mt], b, acc[mt][nt], 0, 0, 0);
        }
        #pragma unroll
        for (int mt = 0; mt < 4; ++mt)
            #pragma unroll
            for (int nt = 0; nt < 4; ++nt)
                #pragma unroll
                for (int rr = 0; rr < 4; ++rr) {
                    const float h = fmaxf(acc[mt][nt][rr] + biasH1[nt], 0.f);
                    const int row = mt * 16 + lgrp * 4 + rr;
                    Hw[row * 72 + nt * 16 + col] = (unsigned short)f2bf(h);
                }
    }

    // ================= L4: hh2 = relu(hh1 @ hw2 + hb2)  [K=64, N=64] ========
    {
        f32x4 acc[4][4];
        #pragma unroll
        for (int mt = 0; mt < 4; ++mt)
            #pragma unroll
            for (int nt = 0; nt < 4; ++nt) acc[mt][nt] = zero;

        #pragma unroll
        for (int ks = 0; ks < 2; ++ks) {
            bf16x8 a[4];
            #pragma unroll
            for (int mt = 0; mt < 4; ++mt)
                a[mt] = *reinterpret_cast<const bf16x8*>(
                    Hw + (mt * 16 + col) * 72 + ks * 32 + lgrp * 8);
            #pragma unroll
            for (int nt = 0; nt < 4; ++nt) {
                const bf16x8 b = *reinterpret_cast<const bf16x8*>(
                    w4t + (nt * 16 + col) * 72 + ks * 32 + lgrp * 8);
                #pragma unroll
                for (int mt = 0; mt < 4; ++mt)
                    acc[mt][nt] = __builtin_amdgcn_mfma_f32_16x16x32_bf16(
                        a[mt], b, acc[mt][nt], 0, 0, 0);
            }
        }
        #pragma unroll
        for (int mt = 0; mt < 4; ++mt)
            #pragma unroll
            for (int nt = 0; nt < 4; ++nt)
                #pragma unroll
                for (int rr = 0; rr < 4; ++rr) {
                    const float h = fmaxf(acc[mt][nt][rr] + biasH2[nt], 0.f);
                    const int row = mt * 16 + lgrp * 4 + rr;
                    Hw[row * 72 + nt * 16 + col] = (unsigned short)f2bf(h);
                }
    }

    // ================= L5: rgb = sigmoid(hh2 @ hw3 + hb3)  [K=64, N=3] ======
    {
        f32x4 acc[4];
        #pragma unroll
        for (int mt = 0; mt < 4; ++mt) acc[mt] = zero;

        #pragma unroll
        for (int ks = 0; ks < 2; ++ks) {
            const bf16x8 b = *reinterpret_cast<const bf16x8*>(
                w5t + col * 72 + ks * 32 + lgrp * 8);
            #pragma unroll
            for (int mt = 0; mt < 4; ++mt) {
                const bf16x8 a = *reinterpret_cast<const bf16x8*>(
                    Hw + (mt * 16 + col) * 72 + ks * 32 + lgrp * 8);
                acc[mt] = __builtin_amdgcn_mfma_f32_16x16x32_bf16(
                    a, b, acc[mt], 0, 0, 0);
            }
        }
        if (col < 3) {
            #pragma unroll
            for (int mt = 0; mt < 4; ++mt)
                #pragma unroll
                for (int rr = 0; rr < 4; ++rr) {
                    const float v = acc[mt][rr] + biasH3;
                    const float rgb = 1.f / (1.f + expf(-v));
                    const int row = mt * 16 + lgrp * 4 + rr;
                    out[(size_t)(blockPt + wave * 64 + row) * 3 + col] = rgb;
                }
        }
    }
}

extern "C" void kernel_launch(void* const* d_in, const int* in_sizes, int n_in,
                              void* d_out, int out_size, void* d_ws, size_t ws_size,
                              hipStream_t stream) {
    const float* positions = (const float*)d_in[0];
    const float* aabb      = (const float*)d_in[1];
    const float* table     = (const float*)d_in[2];
    const float* w1  = (const float*)d_in[3];
    const float* b1  = (const float*)d_in[4];
    const float* w2  = (const float*)d_in[5];
    const float* b2  = (const float*)d_in[6];
    const float* hw1 = (const float*)d_in[7];
    const float* hb1 = (const float*)d_in[8];
    const float* hw2 = (const float*)d_in[9];
    const float* hb2 = (const float*)d_in[10];
    const float* hw3 = (const float*)d_in[11];
    const float* hb3 = (const float*)d_in[12];
    float* out = (float*)d_out;

    const int npts = in_sizes[0] / 3;

    unsigned* encbuf = (unsigned*)d_ws;
    unsigned short* wt =
        (unsigned short*)((char*)d_ws + (size_t)npts * 16 * 4);

    // RES exactly as numpy: float64 pow -> floor -> f32 (matched bit-exact in R1)
    float R[NLV];
    const double bb = exp((log(4096.0) - log(16.0)) / 15.0);
    for (int l = 0; l < NLV; ++l)
        R[l] = (float)floor(16.0 * pow(bb, (double)l));

    enc_kernel<<<(npts * 16) / 256, 256, 0, stream>>>(
        positions, aabb, table, encbuf,
        R[0], R[1], R[2], R[3], R[4], R[5], R[6], R[7],
        R[8], R[9], R[10], R[11], R[12], R[13], R[14], R[15]);

    prep_weights<<<1, 256, 0, stream>>>(w1, w2, hw1, hw2, hw3, wt);

    mlp_kernel<<<npts / 256, 256, 0, stream>>>(
        encbuf, wt, positions, aabb, b1, b2, hb1, hb2, hb3, out, npts);
}

// Round 3
// 398.294 us; speedup vs baseline: 4.0810x; 1.4636x over previous
//
#include <hip/hip_runtime.h>
#include <math.h>

#define NLV 16
#define TBLBITS 19
#define TBLMASK ((1u << TBLBITS) - 1u)

typedef __attribute__((ext_vector_type(8))) short bf16x8;
typedef __attribute__((ext_vector_type(4))) float f32x4;

__device__ __forceinline__ unsigned f2bf(float f) {
    unsigned u = __builtin_bit_cast(unsigned, f);
    return (u + 0x7fffu + ((u >> 16) & 1u)) >> 16;   // RNE to bf16
}

// ---------------- Kernel A: hash-grid encode, one LEVEL per block ----------
// grid = (npts/256, 16).  Output layout: encOut[l * npts + p] (coalesced).
__global__ __launch_bounds__(256)
void enc_kernel(const float* __restrict__ positions,
                const float* __restrict__ aabb,
                const float* __restrict__ table,
                unsigned* __restrict__ encOut, int npts,
                float r0_, float r1_, float r2_, float r3_,
                float r4_, float r5_, float r6_, float r7_,
                float r8_, float r9_, float r10_, float r11_,
                float r12_, float r13_, float r14_, float r15_)
{
    const unsigned l = blockIdx.y;               // wave-uniform level
    const unsigned p = blockIdx.x * 256u + threadIdx.x;

    // uniform select tree -> scalar cselects
    const bool s0 = (l & 1u), s1 = (l & 2u), s2 = (l & 4u), s3 = (l & 8u);
    float a0 = s0 ? r1_  : r0_;
    float a1 = s0 ? r3_  : r2_;
    float a2 = s0 ? r5_  : r4_;
    float a3 = s0 ? r7_  : r6_;
    float a4 = s0 ? r9_  : r8_;
    float a5 = s0 ? r11_ : r10_;
    float a6 = s0 ? r13_ : r12_;
    float a7 = s0 ? r15_ : r14_;
    float c0 = s1 ? a1 : a0;
    float c1 = s1 ? a3 : a2;
    float c2 = s1 ? a5 : a4;
    float c3 = s1 ? a7 : a6;
    float d0 = s2 ? c1 : c0;
    float d1 = s2 ? c3 : c2;
    const float r = s3 ? d1 : d0;

    const float px = positions[p * 3 + 0];
    const float py = positions[p * 3 + 1];
    const float pz = positions[p * 3 + 2];
    const float mnx = aabb[0], mny = aabb[1], mnz = aabb[2];
    const float mxx = aabb[3], mxy = aabb[4], mxz = aabb[5];
    const float x0 = (px - mnx) / (mxx - mnx);
    const float x1 = (py - mny) / (mxy - mny);
    const float x2 = (pz - mnz) / (mxz - mnz);

    const float fx = x0 * r, fy = x1 * r, fz = x2 * r;
    const float gx = floorf(fx), gy = floorf(fy), gz = floorf(fz);
    const unsigned cx = (unsigned)gx, cy = (unsigned)gy, cz = (unsigned)gz;
    const float rx = fx - gx, ry = fy - gy, rz = fz - gz;

    const float* tl = table + ((size_t)l << 20);   // l * TBL * 2 floats
    float e0 = 0.f, e1 = 0.f;
    #pragma unroll
    for (int c = 0; c < 8; ++c) {
        const unsigned hx = cx + ((c >> 2) & 1);
        const unsigned hy = cy + ((c >> 1) & 1);
        const unsigned hz = cz + (c & 1);
        const unsigned h = (hx ^ hy * 2654435761u ^ hz * 805459861u) & TBLMASK;
        const float wx = (c & 4) ? rx : 1.f - rx;
        const float wy = (c & 2) ? ry : 1.f - ry;
        const float wz = (c & 1) ? rz : 1.f - rz;
        const float wgt = wx * wy * wz;
        const float2 f = *reinterpret_cast<const float2*>(tl + ((size_t)h << 1));
        e0 = fmaf(wgt, f.x, e0);
        e1 = fmaf(wgt, f.y, e1);
    }
    encOut[(size_t)l * npts + p] = f2bf(e0) | (f2bf(e1) << 16);
}

// ---------------- Kernel W: transpose/pad/convert weights to bf16 frag layout
//  w1T  @     0: 64 rows, stride 40 (K=32 real 32)        from w1  [32][64]
//  w3T  @  2560: 64 rows, stride 40 (K=32 real 15)        from hw1 [15][64]
//  w2T  @  5120: 16 rows, stride 72 (K=64)                from w2  [64][16]
//  w4T  @  6272: 64 rows, stride 72 (K=64)                from hw2 [64][64]
//  w5T  @ 10880: 16 rows, stride 72 (K=64, real N=3)      from hw3 [64][3]
__global__ __launch_bounds__(256)
void prep_weights(const float* __restrict__ w1, const float* __restrict__ w2,
                  const float* __restrict__ hw1, const float* __restrict__ hw2,
                  const float* __restrict__ hw3, unsigned short* __restrict__ wt)
{
    for (int i = threadIdx.x; i < 12032; i += 256) {
        float v = 0.f;
        if (i < 2560) {
            int n = i / 40, k = i % 40;
            if (k < 32) v = w1[k * 64 + n];
        } else if (i < 5120) {
            int j = i - 2560, n = j / 40, k = j % 40;
            if (k < 15) v = hw1[k * 64 + n];
        } else if (i < 6272) {
            int j = i - 5120, n = j / 72, k = j % 72;
            if (k < 64) v = w2[k * 16 + n];
        } else if (i < 10880) {
            int j = i - 6272, n = j / 72, k = j % 72;
            if (k < 64) v = hw2[k * 64 + n];
        } else {
            int j = i - 10880, n = j / 72, k = j % 72;
            if (k < 64 && n < 3) v = hw3[k * 3 + n];
        }
        wt[i] = (unsigned short)f2bf(v);
    }
}

// ---------------- Kernel B: fused MFMA-bf16 MLP, 256 points / block ---------
// Weights read straight from global (24 KB -> L1-resident). H is per-wave,
// so the kernel is barrier-free.
__global__ __launch_bounds__(256)
void mlp_kernel(const unsigned* __restrict__ enc,        // bf16 pairs [16][npts]
                const unsigned short* __restrict__ wt,   // prepped weights
                const float* __restrict__ positions,
                const float* __restrict__ aabb,
                const float* __restrict__ b1, const float* __restrict__ b2,
                const float* __restrict__ hb1, const float* __restrict__ hb2,
                const float* __restrict__ hb3,
                float* __restrict__ out, int npts)
{
    __shared__ __align__(16) unsigned short H[4][64 * 72];  // per-wave
    __shared__ float sel_lds[256];

    const int tid  = threadIdx.x;
    const int wave = tid >> 6;
    const int lane = tid & 63;
    const int col  = lane & 15;
    const int lgrp = lane >> 4;
    const int blockPt = blockIdx.x * 256;

    // ---- selector for own point (per-wave region of sel_lds; no barrier) ----
    {
        const int gp = blockPt + tid;
        const float px = positions[gp * 3 + 0];
        const float py = positions[gp * 3 + 1];
        const float pz = positions[gp * 3 + 2];
        const float mnx = aabb[0], mny = aabb[1], mnz = aabb[2];
        const float mxx = aabb[3], mxy = aabb[4], mxz = aabb[5];
        const float x0 = (px - mnx) / (mxx - mnx);
        const float x1 = (py - mny) / (mxy - mny);
        const float x2 = (pz - mnz) / (mxz - mnz);
        const bool sel = (x0 > 0.f) && (x0 < 1.f) && (x1 > 0.f) && (x1 < 1.f) &&
                         (x2 > 0.f) && (x2 < 1.f);
        sel_lds[tid] = sel ? 1.f : 0.f;
    }

    // ---- per-lane bias preloads ----
    float bias1[4], biasH1[4], biasH2[4];
    #pragma unroll
    for (int nt = 0; nt < 4; ++nt) {
        bias1[nt]  = b1[nt * 16 + col];
        biasH1[nt] = hb1[nt * 16 + col];
        biasH2[nt] = hb2[nt * 16 + col];
    }
    const float bias2 = b2[col];
    float biasH3 = 0.f;
    if (col < 3) biasH3 = hb3[col];

    // ---- A-frags for layer 1 from [l][p] enc layout ----
    bf16x8 a1[4];
    #pragma unroll
    for (int mt = 0; mt < 4; ++mt) {
        const int ptl = blockPt + wave * 64 + mt * 16 + col;
        uint4 v;
        v.x = enc[(size_t)(lgrp * 4 + 0) * npts + ptl];
        v.y = enc[(size_t)(lgrp * 4 + 1) * npts + ptl];
        v.z = enc[(size_t)(lgrp * 4 + 2) * npts + ptl];
        v.w = enc[(size_t)(lgrp * 4 + 3) * npts + ptl];
        a1[mt] = __builtin_bit_cast(bf16x8, v);
    }

    const unsigned short* w1t = wt;
    const unsigned short* w3t = wt + 2560;
    const unsigned short* w2t = wt + 5120;
    const unsigned short* w4t = wt + 6272;
    const unsigned short* w5t = wt + 10880;
    unsigned short* Hw = H[wave];

    const f32x4 zero = {0.f, 0.f, 0.f, 0.f};

    // ================= L1: h1 = relu(enc @ w1 + b1)  [K=32, N=64] ==========
    {
        f32x4 acc[4][4];
        #pragma unroll
        for (int mt = 0; mt < 4; ++mt)
            #pragma unroll
            for (int nt = 0; nt < 4; ++nt) acc[mt][nt] = zero;

        #pragma unroll
        for (int nt = 0; nt < 4; ++nt) {
            const bf16x8 b = *reinterpret_cast<const bf16x8*>(
                w1t + (nt * 16 + col) * 40 + lgrp * 8);
            #pragma unroll
            for (int mt = 0; mt < 4; ++mt)
                acc[mt][nt] = __builtin_amdgcn_mfma_f32_16x16x32_bf16(
                    a1[mt], b, acc[mt][nt], 0, 0, 0);
        }
        #pragma unroll
        for (int mt = 0; mt < 4; ++mt)
            #pragma unroll
            for (int nt = 0; nt < 4; ++nt)
                #pragma unroll
                for (int rr = 0; rr < 4; ++rr) {
                    const float h = fmaxf(acc[mt][nt][rr] + bias1[nt], 0.f);
                    const int row = mt * 16 + lgrp * 4 + rr;
                    Hw[row * 72 + nt * 16 + col] = (unsigned short)f2bf(h);
                }
    }

    // ================= L2: base = h1 @ w2 + b2  [K=64, N=16] ================
    {
        f32x4 acc[4];
        #pragma unroll
        for (int mt = 0; mt < 4; ++mt) acc[mt] = zero;

        #pragma unroll
        for (int ks = 0; ks < 2; ++ks) {
            const bf16x8 b = *reinterpret_cast<const bf16x8*>(
                w2t + col * 72 + ks * 32 + lgrp * 8);
            #pragma unroll
            for (int mt = 0; mt < 4; ++mt) {
                const bf16x8 a = *reinterpret_cast<const bf16x8*>(
                    Hw + (mt * 16 + col) * 72 + ks * 32 + lgrp * 8);
                acc[mt] = __builtin_amdgcn_mfma_f32_16x16x32_bf16(
                    a, b, acc[mt], 0, 0, 0);
            }
        }
        #pragma unroll
        for (int mt = 0; mt < 4; ++mt)
            #pragma unroll
            for (int rr = 0; rr < 4; ++rr) {
                const float base = acc[mt][rr] + bias2;
                const int row = mt * 16 + lgrp * 4 + rr;
                if (col == 0) {
                    const float dn =
                        expf(base - 1.f) * sel_lds[wave * 64 + row];
                    out[(size_t)npts * 3 + blockPt + wave * 64 + row] = dn;
                } else {
                    Hw[row * 72 + (col - 1)] = (unsigned short)f2bf(base);
                }
            }
        {
            const int row = lane;
            Hw[row * 72 + 15] = 0;
            const uint4 z4 = {0, 0, 0, 0};
            *reinterpret_cast<uint4*>(Hw + row * 72 + 16) = z4;
            *reinterpret_cast<uint4*>(Hw + row * 72 + 24) = z4;
        }
    }

    // ================= L3: hh1 = relu(emb @ hw1 + hb1)  [K=32(15), N=64] ====
    {
        f32x4 acc[4][4];
        #pragma unroll
        for (int mt = 0; mt < 4; ++mt)
            #pragma unroll
            for (int nt = 0; nt < 4; ++nt) acc[mt][nt] = zero;

        bf16x8 a[4];
        #pragma unroll
        for (int mt = 0; mt < 4; ++mt)
            a[mt] = *reinterpret_cast<const bf16x8*>(
                Hw + (mt * 16 + col) * 72 + lgrp * 8);

        #pragma unroll
        for (int nt = 0; nt < 4; ++nt) {
            const bf16x8 b = *reinterpret_cast<const bf16x8*>(
                w3t + (nt * 16 + col) * 40 + lgrp * 8);
            #pragma unroll
            for (int mt = 0; mt < 4; ++mt)
                acc[mt][nt] = __builtin_amdgcn_mfma_f32_16x16x32_bf16(
                    a[mt], b, acc[mt][nt], 0, 0, 0);
        }
        #pragma unroll
        for (int mt = 0; mt < 4; ++mt)
            #pragma unroll
            for (int nt = 0; nt < 4; ++nt)
                #pragma unroll
                for (int rr = 0; rr < 4; ++rr) {
                    const float h = fmaxf(acc[mt][nt][rr] + biasH1[nt], 0.f);
                    const int row = mt * 16 + lgrp * 4 + rr;
                    Hw[row * 72 + nt * 16 + col] = (unsigned short)f2bf(h);
                }
    }

    // ================= L4: hh2 = relu(hh1 @ hw2 + hb2)  [K=64, N=64] ========
    {
        f32x4 acc[4][4];
        #pragma unroll
        for (int mt = 0; mt < 4; ++mt)
            #pragma unroll
            for (int nt = 0; nt < 4; ++nt) acc[mt][nt] = zero;

        #pragma unroll
        for (int ks = 0; ks < 2; ++ks) {
            bf16x8 a[4];
            #pragma unroll
            for (int mt = 0; mt < 4; ++mt)
                a[mt] = *reinterpret_cast<const bf16x8*>(
                    Hw + (mt * 16 + col) * 72 + ks * 32 + lgrp * 8);
            #pragma unroll
            for (int nt = 0; nt < 4; ++nt) {
                const bf16x8 b = *reinterpret_cast<const bf16x8*>(
                    w4t + (nt * 16 + col) * 72 + ks * 32 + lgrp * 8);
                #pragma unroll
                for (int mt = 0; mt < 4; ++mt)
                    acc[mt][nt] = __builtin_amdgcn_mfma_f32_16x16x32_bf16(
                        a[mt], b, acc[mt][nt], 0, 0, 0);
            }
        }
        #pragma unroll
        for (int mt = 0; mt < 4; ++mt)
            #pragma unroll
            for (int nt = 0; nt < 4; ++nt)
                #pragma unroll
                for (int rr = 0; rr < 4; ++rr) {
                    const float h = fmaxf(acc[mt][nt][rr] + biasH2[nt], 0.f);
                    const int row = mt * 16 + lgrp * 4 + rr;
                    Hw[row * 72 + nt * 16 + col] = (unsigned short)f2bf(h);
                }
    }

    // ================= L5: rgb = sigmoid(hh2 @ hw3 + hb3)  [K=64, N=3] ======
    {
        f32x4 acc[4];
        #pragma unroll
        for (int mt = 0; mt < 4; ++mt) acc[mt] = zero;

        #pragma unroll
        for (int ks = 0; ks < 2; ++ks) {
            const bf16x8 b = *reinterpret_cast<const bf16x8*>(
                w5t + col * 72 + ks * 32 + lgrp * 8);
            #pragma unroll
            for (int mt = 0; mt < 4; ++mt) {
                const bf16x8 a = *reinterpret_cast<const bf16x8*>(
                    Hw + (mt * 16 + col) * 72 + ks * 32 + lgrp * 8);
                acc[mt] = __builtin_amdgcn_mfma_f32_16x16x32_bf16(
                    a, b, acc[mt], 0, 0, 0);
            }
        }
        if (col < 3) {
            #pragma unroll
            for (int mt = 0; mt < 4; ++mt)
                #pragma unroll
                for (int rr = 0; rr < 4; ++rr) {
                    const float v = acc[mt][rr] + biasH3;
                    const float rgb = 1.f / (1.f + expf(-v));
                    const int row = mt * 16 + lgrp * 4 + rr;
                    out[(size_t)(blockPt + wave * 64 + row) * 3 + col] = rgb;
                }
        }
    }
}

extern "C" void kernel_launch(void* const* d_in, const int* in_sizes, int n_in,
                              void* d_out, int out_size, void* d_ws, size_t ws_size,
                              hipStream_t stream) {
    const float* positions = (const float*)d_in[0];
    const float* aabb      = (const float*)d_in[1];
    const float* table     = (const float*)d_in[2];
    const float* w1  = (const float*)d_in[3];
    const float* b1  = (const float*)d_in[4];
    const float* w2  = (const float*)d_in[5];
    const float* b2  = (const float*)d_in[6];
    const float* hw1 = (const float*)d_in[7];
    const float* hb1 = (const float*)d_in[8];
    const float* hw2 = (const float*)d_in[9];
    const float* hb2 = (const float*)d_in[10];
    const float* hw3 = (const float*)d_in[11];
    const float* hb3 = (const float*)d_in[12];
    float* out = (float*)d_out;

    const int npts = in_sizes[0] / 3;

    unsigned* encbuf = (unsigned*)d_ws;
    unsigned short* wt =
        (unsigned short*)((char*)d_ws + (size_t)npts * 16 * 4);

    float R[NLV];
    const double bb = exp((log(4096.0) - log(16.0)) / 15.0);
    for (int l = 0; l < NLV; ++l)
        R[l] = (float)floor(16.0 * pow(bb, (double)l));

    dim3 egrid(npts / 256, NLV);
    enc_kernel<<<egrid, 256, 0, stream>>>(
        positions, aabb, table, encbuf, npts,
        R[0], R[1], R[2], R[3], R[4], R[5], R[6], R[7],
        R[8], R[9], R[10], R[11], R[12], R[13], R[14], R[15]);

    prep_weights<<<1, 256, 0, stream>>>(w1, w2, hw1, hw2, hw3, wt);

    mlp_kernel<<<npts / 256, 256, 0, stream>>>(
        encbuf, wt, positions, aabb, b1, b2, hb1, hb2, hb3, out, npts);
}

// Round 5
// 320.746 us; speedup vs baseline: 5.0676x; 1.2418x over previous
//
#include <hip/hip_runtime.h>
#include <math.h>

#define NLV 16
#define TBLBITS 19
#define TBLMASK ((1u << TBLBITS) - 1u)
#define P2 2654435761u
#define P3 805459861u

typedef __attribute__((ext_vector_type(8))) short bf16x8;
typedef __attribute__((ext_vector_type(4))) float f32x4;

__device__ __forceinline__ unsigned f2bf(float f) {
    unsigned u = __builtin_bit_cast(unsigned, f);
    return (u + 0x7fffu + ((u >> 16) & 1u)) >> 16;   // RNE to bf16
}

// ---------------- Kernel A: hash-grid encode, one LEVEL per block ----------
// grid = (npts/256, 16).  Output: encOut[l * npts + p] (coalesced).
// x-pair trick: PRIMES[0]==1 so for even x0 the two x-corners' hash indices
// differ only in bit0 -> one aligned 16B load fetches both float2 entries.
__global__ __launch_bounds__(256)
void enc_kernel(const float* __restrict__ positions,
                const float* __restrict__ aabb,
                const float* __restrict__ table,
                unsigned* __restrict__ encOut, int npts,
                float r0_, float r1_, float r2_, float r3_,
                float r4_, float r5_, float r6_, float r7_,
                float r8_, float r9_, float r10_, float r11_,
                float r12_, float r13_, float r14_, float r15_)
{
    const unsigned l = blockIdx.y;               // wave-uniform level
    const unsigned p = blockIdx.x * 256u + threadIdx.x;

    const bool s0 = (l & 1u), s1 = (l & 2u), s2 = (l & 4u), s3 = (l & 8u);
    float a0 = s0 ? r1_  : r0_;
    float a1 = s0 ? r3_  : r2_;
    float a2 = s0 ? r5_  : r4_;
    float a3 = s0 ? r7_  : r6_;
    float a4 = s0 ? r9_  : r8_;
    float a5 = s0 ? r11_ : r10_;
    float a6 = s0 ? r13_ : r12_;
    float a7 = s0 ? r15_ : r14_;
    float c0 = s1 ? a1 : a0;
    float c1 = s1 ? a3 : a2;
    float c2 = s1 ? a5 : a4;
    float c3 = s1 ? a7 : a6;
    float d0 = s2 ? c1 : c0;
    float d1 = s2 ? c3 : c2;
    const float r = s3 ? d1 : d0;

    const float px = positions[p * 3 + 0];
    const float py = positions[p * 3 + 1];
    const float pz = positions[p * 3 + 2];
    const float mnx = aabb[0], mny = aabb[1], mnz = aabb[2];
    const float mxx = aabb[3], mxy = aabb[4], mxz = aabb[5];
    const float x0 = (px - mnx) / (mxx - mnx);
    const float x1 = (py - mny) / (mxy - mny);
    const float x2 = (pz - mnz) / (mxz - mnz);

    const float fx = x0 * r, fy = x1 * r, fz = x2 * r;
    const float gx = floorf(fx), gy = floorf(fy), gz = floorf(fz);
    const unsigned cx = (unsigned)gx, cy = (unsigned)gy, cz = (unsigned)gz;
    const float rx = fx - gx, ry = fy - gy, rz = fz - gz;

    const float* tl = table + ((size_t)l << 20);   // l * TBL * 2 floats
    float e0 = 0.f, e1 = 0.f;
    const bool xeven = (cx & 1u) == 0u;

    #pragma unroll
    for (int yz = 0; yz < 4; ++yz) {
        const unsigned dy = (yz >> 1) & 1, dz = yz & 1;
        const unsigned base = ((cy + dy) * P2) ^ ((cz + dz) * P3);
        const float wy = dy ? ry : 1.f - ry;
        const float wz = dz ? rz : 1.f - rz;
        const float wyz = wy * wz;
        const float wa = wyz * (1.f - rx);   // weight for x corner 0
        const float wb = wyz * rx;           // weight for x corner 1
        const unsigned i0 = (cx ^ base) & TBLMASK;

        float f0x, f0y, f1x, f1y;
        if (xeven) {
            // both entries live in the aligned 16B block at (i0 & ~1)
            const float4 q = *reinterpret_cast<const float4*>(
                tl + ((size_t)(i0 & ~1u) << 1));
            const bool lo = (i0 & 1u) == 0u;
            f0x = lo ? q.x : q.z;  f0y = lo ? q.y : q.w;
            f1x = lo ? q.z : q.x;  f1y = lo ? q.w : q.y;
        } else {
            const unsigned i1 = ((cx + 1u) ^ base) & TBLMASK;
            const float2 qa = *reinterpret_cast<const float2*>(tl + ((size_t)i0 << 1));
            const float2 qb = *reinterpret_cast<const float2*>(tl + ((size_t)i1 << 1));
            f0x = qa.x; f0y = qa.y; f1x = qb.x; f1y = qb.y;
        }
        e0 = fmaf(wa, f0x, e0); e0 = fmaf(wb, f1x, e0);
        e1 = fmaf(wa, f0y, e1); e1 = fmaf(wb, f1y, e1);
    }
    encOut[(size_t)l * npts + p] = f2bf(e0) | (f2bf(e1) << 16);
}

// ---------------- Kernel W: transpose/pad/convert weights (gridded) --------
//  w1T  @     0: 64 rows, stride 40 (K=32 real 32)        from w1  [32][64]
//  w3T  @  2560: 64 rows, stride 40 (K=32 real 15)        from hw1 [15][64]
//  w2T  @  5120: 16 rows, stride 72 (K=64)                from w2  [64][16]
//  w4T  @  6272: 64 rows, stride 72 (K=64)                from hw2 [64][64]
//  w5T  @ 10880: 16 rows, stride 72 (K=64, real N=3)      from hw3 [64][3]
__global__ __launch_bounds__(256)
void prep_weights(const float* __restrict__ w1, const float* __restrict__ w2,
                  const float* __restrict__ hw1, const float* __restrict__ hw2,
                  const float* __restrict__ hw3, unsigned short* __restrict__ wt)
{
    const int i = blockIdx.x * 256 + threadIdx.x;
    if (i >= 12032) return;
    float v = 0.f;
    if (i < 2560) {
        int n = i / 40, k = i % 40;
        if (k < 32) v = w1[k * 64 + n];
    } else if (i < 5120) {
        int j = i - 2560, n = j / 40, k = j % 40;
        if (k < 15) v = hw1[k * 64 + n];
    } else if (i < 6272) {
        int j = i - 5120, n = j / 72, k = j % 72;
        if (k < 64) v = w2[k * 16 + n];
    } else if (i < 10880) {
        int j = i - 6272, n = j / 72, k = j % 72;
        if (k < 64) v = hw2[k * 64 + n];
    } else {
        int j = i - 10880, n = j / 72, k = j % 72;
        if (k < 64 && n < 3) v = hw3[k * 3 + n];
    }
    wt[i] = (unsigned short)f2bf(v);
}

// ---------------- Kernel B: fused MFMA-bf16 MLP, 32 points / wave ----------
// 4 waves x 32 points = 128 points / block. Barrier-free (H, sel per-wave).
// Weights from global (24 KB, L1/L2-resident).
__global__ __launch_bounds__(256)
void mlp_kernel(const unsigned* __restrict__ enc,        // bf16 pairs [16][npts]
                const unsigned short* __restrict__ wt,   // prepped weights
                const float* __restrict__ positions,
                const float* __restrict__ aabb,
                const float* __restrict__ b1, const float* __restrict__ b2,
                const float* __restrict__ hb1, const float* __restrict__ hb2,
                const float* __restrict__ hb3,
                float* __restrict__ out, int npts)
{
    __shared__ __align__(16) unsigned short H[4][32 * 72];  // per-wave
    __shared__ float sel_lds[128];

    const int tid  = threadIdx.x;
    const int wave = tid >> 6;
    const int lane = tid & 63;
    const int col  = lane & 15;
    const int lgrp = lane >> 4;
    const int blockPt = blockIdx.x * 128;
    const int wavePt  = blockPt + wave * 32;

    // ---- selector: lanes 0..31 of each wave handle its own 32 points ----
    if (lane < 32) {
        const int gp = wavePt + lane;
        const float px = positions[gp * 3 + 0];
        const float py = positions[gp * 3 + 1];
        const float pz = positions[gp * 3 + 2];
        const float mnx = aabb[0], mny = aabb[1], mnz = aabb[2];
        const float mxx = aabb[3], mxy = aabb[4], mxz = aabb[5];
        const float x0 = (px - mnx) / (mxx - mnx);
        const float x1 = (py - mny) / (mxy - mny);
        const float x2 = (pz - mnz) / (mxz - mnz);
        const bool sel = (x0 > 0.f) && (x0 < 1.f) && (x1 > 0.f) && (x1 < 1.f) &&
                         (x2 > 0.f) && (x2 < 1.f);
        sel_lds[wave * 32 + lane] = sel ? 1.f : 0.f;
    }

    // ---- per-lane bias preloads ----
    float bias1[4], biasH1[4], biasH2[4];
    #pragma unroll
    for (int nt = 0; nt < 4; ++nt) {
        bias1[nt]  = b1[nt * 16 + col];
        biasH1[nt] = hb1[nt * 16 + col];
        biasH2[nt] = hb2[nt * 16 + col];
    }
    const float bias2 = b2[col];
    const float biasH3 = (col < 3) ? hb3[col] : 0.f;

    // ---- A-frags for layer 1 from [l][p] enc layout ----
    bf16x8 a1[2];
    #pragma unroll
    for (int mt = 0; mt < 2; ++mt) {
        const int ptl = wavePt + mt * 16 + col;
        uint4 v;
        v.x = enc[(size_t)(lgrp * 4 + 0) * npts + ptl];
        v.y = enc[(size_t)(lgrp * 4 + 1) * npts + ptl];
        v.z = enc[(size_t)(lgrp * 4 + 2) * npts + ptl];
        v.w = enc[(size_t)(lgrp * 4 + 3) * npts + ptl];
        a1[mt] = __builtin_bit_cast(bf16x8, v);
    }

    const unsigned short* w1t = wt;
    const unsigned short* w3t = wt + 2560;
    const unsigned short* w2t = wt + 5120;
    const unsigned short* w4t = wt + 6272;
    const unsigned short* w5t = wt + 10880;
    unsigned short* Hw = H[wave];

    // ================= L1: h1 = relu(enc @ w1 + b1)  [K=32, N=64] ==========
    {
        f32x4 acc[2][4];
        #pragma unroll
        for (int mt = 0; mt < 2; ++mt)
            #pragma unroll
            for (int nt = 0; nt < 4; ++nt) {
                const float b = bias1[nt];
                acc[mt][nt] = (f32x4){b, b, b, b};
            }
        #pragma unroll
        for (int nt = 0; nt < 4; ++nt) {
            const bf16x8 b = *reinterpret_cast<const bf16x8*>(
                w1t + (nt * 16 + col) * 40 + lgrp * 8);
            #pragma unroll
            for (int mt = 0; mt < 2; ++mt)
                acc[mt][nt] = __builtin_amdgcn_mfma_f32_16x16x32_bf16(
                    a1[mt], b, acc[mt][nt], 0, 0, 0);
        }
        #pragma unroll
        for (int mt = 0; mt < 2; ++mt)
            #pragma unroll
            for (int nt = 0; nt < 4; ++nt)
                #pragma unroll
                for (int rr = 0; rr < 4; ++rr) {
                    const float h = fmaxf(acc[mt][nt][rr], 0.f);
                    const int row = mt * 16 + lgrp * 4 + rr;
                    Hw[row * 72 + nt * 16 + col] = (unsigned short)f2bf(h);
                }
    }

    // ================= L2: base = h1 @ w2 + b2  [K=64, N=16] ================
    {
        f32x4 acc[2];
        #pragma unroll
        for (int mt = 0; mt < 2; ++mt)
            acc[mt] = (f32x4){bias2, bias2, bias2, bias2};
        #pragma unroll
        for (int ks = 0; ks < 2; ++ks) {
            const bf16x8 b = *reinterpret_cast<const bf16x8*>(
                w2t + col * 72 + ks * 32 + lgrp * 8);
            #pragma unroll
            for (int mt = 0; mt < 2; ++mt) {
                const bf16x8 a = *reinterpret_cast<const bf16x8*>(
                    Hw + (mt * 16 + col) * 72 + ks * 32 + lgrp * 8);
                acc[mt] = __builtin_amdgcn_mfma_f32_16x16x32_bf16(
                    a, b, acc[mt], 0, 0, 0);
            }
        }
        #pragma unroll
        for (int mt = 0; mt < 2; ++mt)
            #pragma unroll
            for (int rr = 0; rr < 4; ++rr) {
                const float base = acc[mt][rr];
                const int row = mt * 16 + lgrp * 4 + rr;
                if (col == 0) {
                    const float dn = __expf(base - 1.f) * sel_lds[wave * 32 + row];
                    out[(size_t)npts * 3 + wavePt + row] = dn;
                } else {
                    Hw[row * 72 + (col - 1)] = (unsigned short)f2bf(base);
                }
            }
        if (lane < 32) {
            const int row = lane;
            Hw[row * 72 + 15] = 0;
            const uint4 z4 = {0, 0, 0, 0};
            *reinterpret_cast<uint4*>(Hw + row * 72 + 16) = z4;
            *reinterpret_cast<uint4*>(Hw + row * 72 + 24) = z4;
        }
    }

    // ================= L3: hh1 = relu(emb @ hw1 + hb1)  [K=32(15), N=64] ====
    {
        f32x4 acc[2][4];
        #pragma unroll
        for (int mt = 0; mt < 2; ++mt)
            #pragma unroll
            for (int nt = 0; nt < 4; ++nt) {
                const float b = biasH1[nt];
                acc[mt][nt] = (f32x4){b, b, b, b};
            }
        bf16x8 a[2];
        #pragma unroll
        for (int mt = 0; mt < 2; ++mt)
            a[mt] = *reinterpret_cast<const bf16x8*>(
                Hw + (mt * 16 + col) * 72 + lgrp * 8);
        #pragma unroll
        for (int nt = 0; nt < 4; ++nt) {
            const bf16x8 b = *reinterpret_cast<const bf16x8*>(
                w3t + (nt * 16 + col) * 40 + lgrp * 8);
            #pragma unroll
            for (int mt = 0; mt < 2; ++mt)
                acc[mt][nt] = __builtin_amdgcn_mfma_f32_16x16x32_bf16(
                    a[mt], b, acc[mt][nt], 0, 0, 0);
        }
        #pragma unroll
        for (int mt = 0; mt < 2; ++mt)
            #pragma unroll
            for (int nt = 0; nt < 4; ++nt)
                #pragma unroll
                for (int rr = 0; rr < 4; ++rr) {
                    const float h = fmaxf(acc[mt][nt][rr], 0.f);
                    const int row = mt * 16 + lgrp * 4 + rr;
                    Hw[row * 72 + nt * 16 + col] = (unsigned short)f2bf(h);
                }
    }

    // ================= L4: hh2 = relu(hh1 @ hw2 + hb2)  [K=64, N=64] ========
    {
        f32x4 acc[2][4];
        #pragma unroll
        for (int mt = 0; mt < 2; ++mt)
            #pragma unroll
            for (int nt = 0; nt < 4; ++nt) {
                const float b = biasH2[nt];
                acc[mt][nt] = (f32x4){b, b, b, b};
            }
        #pragma unroll
        for (int ks = 0; ks < 2; ++ks) {
            bf16x8 a[2];
            #pragma unroll
            for (int mt = 0; mt < 2; ++mt)
                a[mt] = *reinterpret_cast<const bf16x8*>(
                    Hw + (mt * 16 + col) * 72 + ks * 32 + lgrp * 8);
            #pragma unroll
            for (int nt = 0; nt < 4; ++nt) {
                const bf16x8 b = *reinterpret_cast<const bf16x8*>(
                    w4t + (nt * 16 + col) * 72 + ks * 32 + lgrp * 8);
                #pragma unroll
                for (int mt = 0; mt < 2; ++mt)
                    acc[mt][nt] = __builtin_amdgcn_mfma_f32_16x16x32_bf16(
                        a[mt], b, acc[mt][nt], 0, 0, 0);
            }
        }
        #pragma unroll
        for (int mt = 0; mt < 2; ++mt)
            #pragma unroll
            for (int nt = 0; nt < 4; ++nt)
                #pragma unroll
                for (int rr = 0; rr < 4; ++rr) {
                    const float h = fmaxf(acc[mt][nt][rr], 0.f);
                    const int row = mt * 16 + lgrp * 4 + rr;
                    Hw[row * 72 + nt * 16 + col] = (unsigned short)f2bf(h);
                }
    }

    // ================= L5: rgb = sigmoid(hh2 @ hw3 + hb3)  [K=64, N=3] ======
    {
        f32x4 acc[2];
        #pragma unroll
        for (int mt = 0; mt < 2; ++mt)
            acc[mt] = (f32x4){biasH3, biasH3, biasH3, biasH3};
        #pragma unroll
        for (int ks = 0; ks < 2; ++ks) {
            const bf16x8 b = *reinterpret_cast<const bf16x8*>(
                w5t + col * 72 + ks * 32 + lgrp * 8);
            #pragma unroll
            for (int mt = 0; mt < 2; ++mt) {
                const bf16x8 a = *reinterpret_cast<const bf16x8*>(
                    Hw + (mt * 16 + col) * 72 + ks * 32 + lgrp * 8);
                acc[mt] = __builtin_amdgcn_mfma_f32_16x16x32_bf16(
                    a, b, acc[mt], 0, 0, 0);
            }
        }
        if (col < 3) {
            #pragma unroll
            for (int mt = 0; mt < 2; ++mt)
                #pragma unroll
                for (int rr = 0; rr < 4; ++rr) {
                    const float v = acc[mt][rr];
                    const float rgb = 1.f / (1.f + __expf(-v));
                    const int row = mt * 16 + lgrp * 4 + rr;
                    out[(size_t)(wavePt + row) * 3 + col] = rgb;
                }
        }
    }
}

extern "C" void kernel_launch(void* const* d_in, const int* in_sizes, int n_in,
                              void* d_out, int out_size, void* d_ws, size_t ws_size,
                              hipStream_t stream) {
    const float* positions = (const float*)d_in[0];
    const float* aabb      = (const float*)d_in[1];
    const float* table     = (const float*)d_in[2];
    const float* w1  = (const float*)d_in[3];
    const float* b1  = (const float*)d_in[4];
    const float* w2  = (const float*)d_in[5];
    const float* b2  = (const float*)d_in[6];
    const float* hw1 = (const float*)d_in[7];
    const float* hb1 = (const float*)d_in[8];
    const float* hw2 = (const float*)d_in[9];
    const float* hb2 = (const float*)d_in[10];
    const float* hw3 = (const float*)d_in[11];
    const float* hb3 = (const float*)d_in[12];
    float* out = (float*)d_out;

    const int npts = in_sizes[0] / 3;

    unsigned* encbuf = (unsigned*)d_ws;
    unsigned short* wt =
        (unsigned short*)((char*)d_ws + (size_t)npts * 16 * 4);

    float R[NLV];
    const double bb = exp((log(4096.0) - log(16.0)) / 15.0);
    for (int l = 0; l < NLV; ++l)
        R[l] = (float)floor(16.0 * pow(bb, (double)l));

    // prep first (independent of enc) and fully parallel
    prep_weights<<<47, 256, 0, stream>>>(w1, w2, hw1, hw2, hw3, wt);

    dim3 egrid(npts / 256, NLV);
    enc_kernel<<<egrid, 256, 0, stream>>>(
        positions, aabb, table, encbuf, npts,
        R[0], R[1], R[2], R[3], R[4], R[5], R[6], R[7],
        R[8], R[9], R[10], R[11], R[12], R[13], R[14], R[15]);

    mlp_kernel<<<npts / 128, 256, 0, stream>>>(
        encbuf, wt, positions, aabb, b1, b2, hb1, hb2, hb3, out, npts);
}